// Round 19
// baseline (130.886 us; speedup 1.0000x reference)
//
#include <hip/hip_runtime.h>

// QGraphAttention: B=512, NA=8, OB=160, SD=256, H=4, GD=64, KD=65, NU=32
// Inputs: float32. Outputs: float32 concat: [512] | [16384] attn | [67108864] dense.
// R19: decompose K2 — hyper (832 blocks) and fill-B (2048 blocks) run as
// SEPARATE serial launches instead of fused. Single-variable vs R18 (95.5us).
// Readout: ~80 -> interference confirmed; ~95 -> additive/fill-bound; >105 ->
// fusion overlap was real, 95 is the floor.
// ws: kv[4096][65] | keys_acc[4096][65] | WhTr[5200][160] bf16 (3.79 MB), tiered.

typedef short short8v __attribute__((ext_vector_type(8)));
typedef float float4v __attribute__((ext_vector_type(4)));

#define NBATCH 512
#define NAG 8
#define OBD 160
#define SDD 256
#define NHD 4
#define GDD 64
#define NKD 65
#define NCOL 4225
#define NNODE 4096
#define OUT1_OFF 512
#define OUT2_OFF 16896
#define DENSE_N4 16777216
#define NFILL 2048
#define NPREP 660
#define NZERO 260
#define NSPLIT_R 13           // j-splits: 13 x 5 j = 65
#define NHYP (NSPLIT_R * 64)  // 832 hyper blocks
#define PCOL 5200             // 65 j x 80 padded k
#define NSPLIT_F 8            // fallback path splits
#define CPS 529
#define KVN ((size_t)NNODE * NKD)
#define WHT_OFF (2 * KVN * 4)
#define WS_NEED (WHT_OFF + (size_t)PCOL * OBD * 2)

// fill partition (float4 units)
#define NF1 768
#define F1_N4 3145728         // 48 MB during k_pre
#define NF3 512
#define F3_N4 1310720         // 20 MB during k_attn
#define F2_END (DENSE_N4 - F3_N4)

__device__ __forceinline__ ushort f2b(float f) {
    union { float f; uint i; } x; x.f = f;
    uint r = (x.i + 0x7FFFu + ((x.i >> 16) & 1u)) >> 16;
    return (ushort)r;
}

// zero-fill [i,hi) of dense (float4 units), skipping per-row alpha spans (NT).
__device__ __forceinline__ void fill_range(float4v* __restrict__ d4,
                                           size_t i, size_t stride, size_t hi)
{
    float4v z = {0.f, 0.f, 0.f, 0.f};
    for (; i < hi; i += stride) {
        uint off4 = (uint)i & 4095u;              // f4 within node row
        uint span4 = ((uint)(i >> 15)) << 3;      // batch*8
        if (off4 - span4 < 8u) continue;          // skip alpha span
        __builtin_nontemporal_store(z, d4 + i);
    }
}

// ---- K1: [0,512) GAT | [512,1172) prep | [1172,1432) zero | [1432,2200) fill A ----
__global__ __launch_bounds__(256) void k_pre(
    const float* __restrict__ aq, const float* __restrict__ obs,
    const float* __restrict__ Wg, const float* __restrict__ bg,
    const float* __restrict__ asrc, const float* __restrict__ adst,
    const float* __restrict__ Wh,
    float* __restrict__ kv, float* __restrict__ keys_acc,
    ushort* __restrict__ WhTr, float* __restrict__ dense, int do_prep)
{
    int blk = blockIdx.x, t = threadIdx.x;

    if (blk >= NBATCH) {
        int r = blk - NBATCH;
        if (r < NPREP) {          // build j-major padded WhTr[p=j*80+k][kk]
            if (!do_prep) return;
            for (int i = r * 256 + t; i < PCOL * OBD; i += NPREP * 256) {
                int p = i / OBD, kk = i - p * OBD;
                int j = p / 80, k = p - j * 80;
                WhTr[i] = (k < NKD) ? f2b(Wh[(size_t)kk * NCOL + k * NKD + j]) : (ushort)0;
            }
        } else if (r < NPREP + NZERO) {     // zero keys_acc (66560 float4)
            int z4 = (r - NPREP) * 256 + t;
            ((float4v*)keys_acc)[z4] = float4v{0.f, 0.f, 0.f, 0.f};
        } else {                  // fill chunk A: [0, F1_N4)
            int fb = r - NPREP - NZERO;
            fill_range((float4v*)dense, (size_t)fb * 256 + t,
                       (size_t)NF1 * 256, F1_N4);
        }
        return;
    }

    int b = blk;
    __shared__ float obs_s[NAG][OBD];
    __shared__ float h_s[NAG][GDD];
    __shared__ float u_s[NAG][NHD], v_s[NAG][NHD];
    __shared__ float al_s[NAG][NAG][NHD];
    __shared__ float c_s[NAG][NAG];

    const float* ob = obs + (size_t)b * (NAG * OBD);
    for (int u = t; u < NAG * OBD; u += 256) obs_s[u / OBD][u % OBD] = ob[u];
    __syncthreads();

    {   // h = obs @ W_gnn + b_gnn
        int g = t & 63, i0 = t >> 6;
        float a0 = bg[g], a1 = a0;
        for (int c = 0; c < OBD; ++c) {
            float w = Wg[c * GDD + g];
            a0 += obs_s[i0][c] * w;
            a1 += obs_s[i0 + 4][c] * w;
        }
        h_s[i0][g] = a0; h_s[i0 + 4][g] = a1;
    }
    __syncthreads();

    if (t < 64) {
        int i = (t >> 2) & 7, hd = t & 3;
        const float* av = (t >= 32) ? adst : asrc;
        float a = 0.f;
        for (int g = 0; g < GDD; ++g) a += h_s[i][g] * av[hd * GDD + g];
        if (t >= 32) v_s[i][hd] = a; else u_s[i][hd] = a;
    }
    __syncthreads();

    if (t < 32) {   // per-(dst,head) softmax
        int d = t >> 2, hd = t & 3;
        float e[NAG], m = -1e30f;
        for (int s = 0; s < NAG; ++s) {
            if (s == d) { e[s] = -1e30f; continue; }
            float x = u_s[s][hd] + v_s[d][hd];
            x = x > 0.f ? x : 0.2f * x;
            e[s] = x; if (x > m) m = x;
        }
        float sum = 0.f;
        for (int s = 0; s < NAG; ++s) {
            float ex = (s == d) ? 0.f : expf(e[s] - m);
            sum += ex; al_s[s][d][hd] = ex;
        }
        float inv = 1.f / (sum + 1e-16f);
        for (int s = 0; s < NAG; ++s) al_s[s][d][hd] *= inv;
    }
    __syncthreads();

    if (t < 64) {
        int s = t >> 3, d = t & 7;
        c_s[s][d] = 0.25f * (al_s[s][d][0] + al_s[s][d][1] + al_s[s][d][2] + al_s[s][d][3]);
    }
    __syncthreads();

    {   // agg + relu -> keysvec[.][1+g]
        int g = t & 63, d0 = t >> 6;
        for (int dd = d0; dd < NAG; dd += 4) {
            float a = 0.f;
            for (int s = 0; s < NAG; ++s) a += c_s[s][dd] * h_s[s][g];
            a = a > 0.f ? a : 0.f;
            kv[(size_t)(b * NAG + dd) * NKD + 1 + g] = a;
        }
    }
    if (t < NAG) kv[(size_t)(b * NAG + t) * NKD] = aq[b * NAG + t];

    {   // full 32-float alpha span per src row (incl. diagonal zeros)
        int s = t >> 5, pos = t & 31, d = pos >> 2, hd = pos & 3;
        float v = (d == s) ? 0.f : al_s[s][d][hd];
        dense[(size_t)(b * NAG + s) * (NNODE * NHD) + b * 32 + pos] = v;
    }
}

// ---------- K2a: hyper v5 ONLY (832 blocks) ----------
__global__ __launch_bounds__(256) void k_hyper(
    const float* __restrict__ obs, const ushort* __restrict__ WhTr,
    const float* __restrict__ bh, const float* __restrict__ kv,
    float* __restrict__ keys_acc)
{
    int t = threadIdx.x;
    __shared__ float kv_s[64][NKD];
    __shared__ float bh_s[5][80];

    int sid = blockIdx.x % NSPLIT_R, mb = blockIdx.x / NSPLIT_R;
    int lane = t & 63, w = t >> 6;
    int q = lane >> 4, col = lane & 15;
    int j0 = sid * 5;

    for (int u = t; u < 64 * NKD; u += 256)
        ((float*)kv_s)[u] = kv[(size_t)(mb * 64) * NKD + u];
    for (int u = t; u < 400; u += 256) {
        int jj = u / 80, k = u - jj * 80;
        bh_s[jj][k] = (k < NKD) ? bh[k * NKD + j0 + jj] : 0.f;
    }

    int row_g = mb * 64 + w * 16 + col;
    short8v a8[5];
    #pragma unroll
    for (int ks = 0; ks < 5; ++ks) {
        const float* p = obs + (size_t)row_g * OBD + ks * 32 + q * 8;
        float4v lo = *(const float4v*)p;
        float4v hi = *(const float4v*)(p + 4);
        a8[ks] = short8v{(short)f2b(lo[0]), (short)f2b(lo[1]), (short)f2b(lo[2]), (short)f2b(lo[3]),
                         (short)f2b(hi[0]), (short)f2b(hi[1]), (short)f2b(hi[2]), (short)f2b(hi[3])};
    }
    __syncthreads();

    int rl = w * 16 + q * 4;                 // C rows rl..rl+3 (m89 mapping)
    for (int jj = 0; jj < 5; ++jj) {
        float sacc[4] = {0.f, 0.f, 0.f, 0.f};
        #pragma unroll
        for (int c5 = 0; c5 < 5; ++c5) {
            int k = c5 * 16 + col;           // padded key index [0,80)
            int p = sid * 400 + jj * 80 + k;
            const ushort* bp = WhTr + (size_t)p * OBD;
            float4v acc = {0.f, 0.f, 0.f, 0.f};
            #pragma unroll
            for (int ks = 0; ks < 5; ++ks) {
                short8v b8 = *(const short8v*)(bp + ks * 32 + q * 8);
                acc = __builtin_amdgcn_mfma_f32_16x16x32_bf16(a8[ks], b8, acc, 0, 0, 0);
            }
            float bias = bh_s[jj][k];
            #pragma unroll
            for (int r = 0; r < 4; ++r) {
                float kw = (k < NKD) ? kv_s[rl + r][k] : 0.f;
                sacc[r] += kw * fabsf(acc[r] + bias);
            }
        }
        #pragma unroll
        for (int r = 0; r < 4; ++r) {
            float v = sacc[r];
            v += __shfl_xor(v, 1);
            v += __shfl_xor(v, 2);
            v += __shfl_xor(v, 4);
            v += __shfl_xor(v, 8);
            if (col == 0)
                atomicAdd(&keys_acc[(size_t)(mb * 64 + rl + r) * NKD + j0 + jj], v);
        }
    }
}

// ---------- K2b: fill chunk B ONLY (2048 blocks) ----------
__global__ __launch_bounds__(256) void k_fillB(float* __restrict__ dense)
{
    fill_range((float4v*)dense,
               (size_t)F1_N4 + (size_t)blockIdx.x * 256 + threadIdx.x,
               (size_t)NFILL * 256, F2_END);
}

// ---------- K2 fallback (ws too small): f32 Wh loads, LDS ak, global atomics ----------
__global__ __launch_bounds__(256) void k_hyper_f32(
    const float* __restrict__ obs, const float* __restrict__ Wh,
    const float* __restrict__ bh, const float* __restrict__ kv,
    float* __restrict__ keys_acc)
{
    __shared__ float kv_s[64][NKD];
    __shared__ float ak[64][NKD];
    int t = threadIdx.x;

    int ns = blockIdx.x & 7, mb = blockIdx.x >> 3;
    int lane = t & 63, w = t >> 6;
    int q = lane >> 4, col = lane & 15;
    int cstart = ns * CPS;
    int cend = NCOL < cstart + CPS ? NCOL : cstart + CPS;

    for (int u = t; u < 64 * NKD; u += 256) {
        ((float*)kv_s)[u] = kv[(size_t)(mb * 64) * NKD + u];
        ((float*)ak)[u] = 0.f;
    }

    int row_g = mb * 64 + w * 16 + col;
    short8v a8[5];
    #pragma unroll
    for (int ks = 0; ks < 5; ++ks) {
        const float* p = obs + (size_t)row_g * OBD + ks * 32 + q * 8;
        float4v lo = *(const float4v*)p;
        float4v hi = *(const float4v*)(p + 4);
        a8[ks] = short8v{(short)f2b(lo[0]), (short)f2b(lo[1]), (short)f2b(lo[2]), (short)f2b(lo[3]),
                         (short)f2b(hi[0]), (short)f2b(hi[1]), (short)f2b(hi[2]), (short)f2b(hi[3])};
    }
    __syncthreads();

    for (int cb = cstart; cb < cend; cb += 16) {
        int c2 = cb + col;
        uint cc = (uint)(c2 < NCOL ? c2 : NCOL - 1);
        float4v acc = {0.f, 0.f, 0.f, 0.f};
        #pragma unroll
        for (int ks = 0; ks < 5; ++ks) {
            uint kbase = (uint)(ks * 32 + q * 8) * (uint)NCOL + cc;
            short8v b8;
            #pragma unroll
            for (int r = 0; r < 8; ++r)
                b8[r] = (short)f2b(Wh[kbase + (uint)r * (uint)NCOL]);
            acc = __builtin_amdgcn_mfma_f32_16x16x32_bf16(a8[ks], b8, acc, 0, 0, 0);
        }
        if (c2 < cend) {
            float bias = bh[c2];
            int k2 = c2 / NKD, j = c2 - k2 * NKD;
            #pragma unroll
            for (int r = 0; r < 4; ++r) {
                int rl = w * 16 + q * 4 + r;
                ak[rl][j] += kv_s[rl][k2] * fabsf(acc[r] + bias);
            }
        }
    }
    __syncthreads();

    for (int u = t; u < 64 * NKD; u += 256)
        atomicAdd(&keys_acc[(size_t)(mb * 64) * NKD + u], ((float*)ak)[u]);
}

// ---------- K3: [0,512) attention | [512,1024) fill chunk C ----------
__global__ __launch_bounds__(256) void k_attn(
    const float* __restrict__ aq, const float* __restrict__ states,
    const float* __restrict__ keys_acc,
    const float* __restrict__ Wq, const float* __restrict__ Wk,
    const float* __restrict__ Wv1, const float* __restrict__ bv1,
    const float* __restrict__ Wv2, const float* __restrict__ bv2,
    const float* __restrict__ Ww1, const float* __restrict__ bw1,
    const float* __restrict__ Ww2, const float* __restrict__ bw2,
    float* __restrict__ out, float* __restrict__ dense)
{
    int t = threadIdx.x;
    if (blockIdx.x >= NBATCH) {           // fill chunk C: [F2_END, DENSE_N4)
        int fb = blockIdx.x - NBATCH;
        fill_range((float4v*)dense, (size_t)F2_END + (size_t)fb * 256 + t,
                   (size_t)NF3 * 256, DENSE_N4);
        return;
    }

    int b = blockIdx.x;
    __shared__ float st_s[SDD];
    __shared__ float keys_s[NAG][NKD];
    __shared__ float q_s[32], h1_s[64], hv_s[32];
    __shared__ float kp_s[NAG][32];
    __shared__ float oh_s[NHD], hw_s[NHD];

    st_s[t] = states[(size_t)b * SDD + t];
    for (int u = t; u < NAG * NKD; u += 256) {
        int n = u / NKD, j = u - NKD * n;
        float s = keys_acc[(size_t)(b * NAG + n) * NKD + j];
        keys_s[n][j] = s > 0.f ? s : (expf(s) - 1.f);      // elu
    }
    __syncthreads();

    if (t < 32) {
        float a = 0.f;
        for (int c = 0; c < SDD; ++c) a += st_s[c] * Wq[c * 32 + t];
        q_s[t] = a;
    } else if (t < 96) {
        int z = t - 32; float a = bw1[z];
        for (int c = 0; c < SDD; ++c) a += st_s[c] * Ww1[c * 64 + z];
        h1_s[z] = fmaxf(a, 0.f);
    } else if (t < 128) {
        int z = t - 96; float a = bv1[z];
        for (int c = 0; c < SDD; ++c) a += st_s[c] * Wv1[c * 32 + z];
        hv_s[z] = fmaxf(a, 0.f);
    }
    __syncthreads();

    {   // k-proj
        int i = t >> 5, u = t & 31;
        float a = 0.f;
        for (int j = 0; j < NKD; ++j) a += keys_s[i][j] * Wk[j * 32 + u];
        kp_s[i][u] = a;
    }
    __syncthreads();

    if (t < NHD) {
        int hd = t;
        float sc[NAG], m = -1e30f;
        for (int i = 0; i < NAG; ++i) {
            float a = 0.f;
            for (int dd = 0; dd < 8; ++dd) a += q_s[hd * 8 + dd] * kp_s[i][hd * 8 + dd];
            a *= 0.35355339059327373f;
            sc[i] = a; if (a > m) m = a;
        }
        float sum = 0.f;
        for (int i = 0; i < NAG; ++i) { sc[i] = expf(sc[i] - m); sum += sc[i]; }
        float inv = 1.f / sum, oh = 0.f;
        for (int i = 0; i < NAG; ++i) {
            float at = sc[i] * inv;
            out[OUT1_OFF + (size_t)(b * NHD + hd) * NAG + i] = at;
            oh += at * aq[b * NAG + i];
        }
        oh_s[hd] = oh;
        float hw = bw2[hd];
        for (int z = 0; z < 64; ++z) hw += h1_s[z] * Ww2[z * NHD + hd];
        hw_s[hd] = hw * hw;
    }
    __syncthreads();

    if (t == 0) {
        float v = bv2[0];
        for (int z = 0; z < 32; ++z) v += hv_s[z] * Wv2[z];
        float qt = 0.f;
        for (int hd = 0; hd < NHD; ++hd) qt += oh_s[hd] * hw_s[hd];
        out[b] = qt + v;
    }
}

extern "C" void kernel_launch(void* const* d_in, const int* in_sizes, int n_in,
                              void* d_out, int out_size, void* d_ws, size_t ws_size,
                              hipStream_t stream) {
    const float* aq   = (const float*)d_in[0];
    const float* obs  = (const float*)d_in[1];
    const float* st   = (const float*)d_in[2];
    const float* Wg   = (const float*)d_in[4];
    const float* bg   = (const float*)d_in[5];
    const float* asrc = (const float*)d_in[6];
    const float* adst = (const float*)d_in[7];
    const float* Wh   = (const float*)d_in[8];
    const float* bh   = (const float*)d_in[9];
    const float* Wq_  = (const float*)d_in[10];
    const float* Wk_  = (const float*)d_in[11];
    const float* Wv1  = (const float*)d_in[12];
    const float* bv1  = (const float*)d_in[13];
    const float* Wv2  = (const float*)d_in[14];
    const float* bv2  = (const float*)d_in[15];
    const float* Ww1  = (const float*)d_in[16];
    const float* bw1  = (const float*)d_in[17];
    const float* Ww2  = (const float*)d_in[18];
    const float* bw2  = (const float*)d_in[19];
    float* out = (float*)d_out;
    float* dense = out + OUT2_OFF;

    float*  kv       = (float*)d_ws;                        // [4096][65]
    float*  keys_acc = kv + KVN;                            // [4096][65]
    ushort* WhTr     = (ushort*)((char*)d_ws + WHT_OFF);    // [5200][160] bf16
    int rpath = (ws_size >= WS_NEED) ? 1 : 0;

    // K1: gat | scattered prep | zero keys_acc | fill A
    k_pre<<<NBATCH + NPREP + NZERO + NF1, 256, 0, stream>>>(
        aq, obs, Wg, bg, asrc, adst, Wh, kv, keys_acc, WhTr, dense, rpath);

    // K2a: hyper standalone
    if (rpath)
        k_hyper<<<NHYP, 256, 0, stream>>>(obs, WhTr, bh, kv, keys_acc);
    else
        k_hyper_f32<<<NSPLIT_F * 64, 256, 0, stream>>>(obs, Wh, bh, kv, keys_acc);

    // K2b: fill B standalone
    k_fillB<<<NFILL, 256, 0, stream>>>(dense);

    // K3: attention | fill C
    k_attn<<<NBATCH + NF3, 256, 0, stream>>>(aq, st, keys_acc, Wq_, Wk_, Wv1, bv1,
                                             Wv2, bv2, Ww1, bw1, Ww2, bw2, out, dense);
}

// Round 20
// 95.031 us; speedup vs baseline: 1.3773x; 1.3773x over previous
//
#include <hip/hip_runtime.h>

// QGraphAttention: B=512, NA=8, OB=160, SD=256, H=4, GD=64, KD=65, NU=32
// Inputs: float32. Outputs: float32 concat: [512] | [16384] attn | [67108864] dense.
// R20: R16 exact (best, 95.2us; fused hyper||fill proven essential by R19's
// +35us unfuse) + s_setprio(1) around hyper role's loop (wave-role arbitration:
// hyper waves vs fill waves co-resident on CUs — the setprio-favorable regime).
// ws: kv[4096][65] | keys_acc[4096][65] | WhTr[5200][160] bf16 (3.79 MB), tiered.

typedef short short8v __attribute__((ext_vector_type(8)));
typedef float float4v __attribute__((ext_vector_type(4)));

#define NBATCH 512
#define NAG 8
#define OBD 160
#define SDD 256
#define NHD 4
#define GDD 64
#define NKD 65
#define NCOL 4225
#define NNODE 4096
#define OUT1_OFF 512
#define OUT2_OFF 16896
#define DENSE_N4 16777216
#define NFILL 2048
#define NPREP 660
#define NZERO 260
#define NSPLIT_R 13           // j-splits: 13 x 5 j = 65
#define NHYP (NSPLIT_R * 64)  // 832 hyper blocks
#define PCOL 5200             // 65 j x 80 padded k
#define NSPLIT_F 8            // fallback path splits
#define CPS 529
#define KVN ((size_t)NNODE * NKD)
#define WHT_OFF (2 * KVN * 4)
#define WS_NEED (WHT_OFF + (size_t)PCOL * OBD * 2)

// fill partition (float4 units)
#define NF1 768
#define F1_N4 3145728         // 48 MB during k_pre
#define NF3 512
#define F3_N4 1310720         // 20 MB during k_attn
#define F2_END (DENSE_N4 - F3_N4)

__device__ __forceinline__ ushort f2b(float f) {
    union { float f; uint i; } x; x.f = f;
    uint r = (x.i + 0x7FFFu + ((x.i >> 16) & 1u)) >> 16;
    return (ushort)r;
}

// zero-fill [i,hi) of dense (float4 units), skipping per-row alpha spans
__device__ __forceinline__ void fill_range(float4v* __restrict__ d4,
                                           size_t i, size_t stride, size_t hi)
{
    float4v z = {0.f, 0.f, 0.f, 0.f};
    for (; i < hi; i += stride) {
        uint off4 = (uint)i & 4095u;              // f4 within node row
        uint span4 = ((uint)(i >> 15)) << 3;      // batch*8
        if (off4 - span4 < 8u) continue;          // skip alpha span
        d4[i] = z;
    }
}

// ---- K1: [0,512) GAT | [512,1172) prep | [1172,1432) zero | [1432,2200) fill A ----
__global__ __launch_bounds__(256) void k_pre(
    const float* __restrict__ aq, const float* __restrict__ obs,
    const float* __restrict__ Wg, const float* __restrict__ bg,
    const float* __restrict__ asrc, const float* __restrict__ adst,
    const float* __restrict__ Wh,
    float* __restrict__ kv, float* __restrict__ keys_acc,
    ushort* __restrict__ WhTr, float* __restrict__ dense, int do_prep)
{
    int blk = blockIdx.x, t = threadIdx.x;

    if (blk >= NBATCH) {
        int r = blk - NBATCH;
        if (r < NPREP) {          // build j-major padded WhTr[p=j*80+k][kk]
            if (!do_prep) return;
            for (int i = r * 256 + t; i < PCOL * OBD; i += NPREP * 256) {
                int p = i / OBD, kk = i - p * OBD;
                int j = p / 80, k = p - j * 80;
                WhTr[i] = (k < NKD) ? f2b(Wh[(size_t)kk * NCOL + k * NKD + j]) : (ushort)0;
            }
        } else if (r < NPREP + NZERO) {     // zero keys_acc (66560 float4)
            int z4 = (r - NPREP) * 256 + t;
            ((float4v*)keys_acc)[z4] = float4v{0.f, 0.f, 0.f, 0.f};
        } else {                  // fill chunk A: [0, F1_N4)
            int fb = r - NPREP - NZERO;
            fill_range((float4v*)dense, (size_t)fb * 256 + t,
                       (size_t)NF1 * 256, F1_N4);
        }
        return;
    }

    int b = blk;
    __shared__ float obs_s[NAG][OBD];
    __shared__ float h_s[NAG][GDD];
    __shared__ float u_s[NAG][NHD], v_s[NAG][NHD];
    __shared__ float al_s[NAG][NAG][NHD];
    __shared__ float c_s[NAG][NAG];

    const float* ob = obs + (size_t)b * (NAG * OBD);
    for (int u = t; u < NAG * OBD; u += 256) obs_s[u / OBD][u % OBD] = ob[u];
    __syncthreads();

    {   // h = obs @ W_gnn + b_gnn
        int g = t & 63, i0 = t >> 6;
        float a0 = bg[g], a1 = a0;
        for (int c = 0; c < OBD; ++c) {
            float w = Wg[c * GDD + g];
            a0 += obs_s[i0][c] * w;
            a1 += obs_s[i0 + 4][c] * w;
        }
        h_s[i0][g] = a0; h_s[i0 + 4][g] = a1;
    }
    __syncthreads();

    if (t < 64) {
        int i = (t >> 2) & 7, hd = t & 3;
        const float* av = (t >= 32) ? adst : asrc;
        float a = 0.f;
        for (int g = 0; g < GDD; ++g) a += h_s[i][g] * av[hd * GDD + g];
        if (t >= 32) v_s[i][hd] = a; else u_s[i][hd] = a;
    }
    __syncthreads();

    if (t < 32) {   // per-(dst,head) softmax
        int d = t >> 2, hd = t & 3;
        float e[NAG], m = -1e30f;
        for (int s = 0; s < NAG; ++s) {
            if (s == d) { e[s] = -1e30f; continue; }
            float x = u_s[s][hd] + v_s[d][hd];
            x = x > 0.f ? x : 0.2f * x;
            e[s] = x; if (x > m) m = x;
        }
        float sum = 0.f;
        for (int s = 0; s < NAG; ++s) {
            float ex = (s == d) ? 0.f : expf(e[s] - m);
            sum += ex; al_s[s][d][hd] = ex;
        }
        float inv = 1.f / (sum + 1e-16f);
        for (int s = 0; s < NAG; ++s) al_s[s][d][hd] *= inv;
    }
    __syncthreads();

    if (t < 64) {
        int s = t >> 3, d = t & 7;
        c_s[s][d] = 0.25f * (al_s[s][d][0] + al_s[s][d][1] + al_s[s][d][2] + al_s[s][d][3]);
    }
    __syncthreads();

    {   // agg + relu -> keysvec[.][1+g]
        int g = t & 63, d0 = t >> 6;
        for (int dd = d0; dd < NAG; dd += 4) {
            float a = 0.f;
            for (int s = 0; s < NAG; ++s) a += c_s[s][dd] * h_s[s][g];
            a = a > 0.f ? a : 0.f;
            kv[(size_t)(b * NAG + dd) * NKD + 1 + g] = a;
        }
    }
    if (t < NAG) kv[(size_t)(b * NAG + t) * NKD] = aq[b * NAG + t];

    {   // full 32-float alpha span per src row (incl. diagonal zeros)
        int s = t >> 5, pos = t & 31, d = pos >> 2, hd = pos & 3;
        float v = (d == s) ? 0.f : al_s[s][d][hd];
        dense[(size_t)(b * NAG + s) * (NNODE * NHD) + b * 32 + pos] = v;
    }
}

// ---------- K2 primary: [0,832) hyper v5 (setprio) | [832,2880) fill chunk B ----------
__global__ __launch_bounds__(256) void k_fuse_r(
    const float* __restrict__ obs, const ushort* __restrict__ WhTr,
    const float* __restrict__ bh, const float* __restrict__ kv,
    float* __restrict__ keys_acc, float* __restrict__ dense)
{
    int t = threadIdx.x;

    if (blockIdx.x >= NHYP) {             // ---- fill role: [F1_N4, F2_END) ----
        int fb = blockIdx.x - NHYP;
        fill_range((float4v*)dense, (size_t)F1_N4 + (size_t)fb * 256 + t,
                   (size_t)NFILL * 256, F2_END);
        return;
    }

    __shared__ float kv_s[64][NKD];
    __shared__ float bh_s[5][80];

    int sid = blockIdx.x % NSPLIT_R, mb = blockIdx.x / NSPLIT_R;
    int lane = t & 63, w = t >> 6;
    int q = lane >> 4, col = lane & 15;
    int j0 = sid * 5;

    for (int u = t; u < 64 * NKD; u += 256)
        ((float*)kv_s)[u] = kv[(size_t)(mb * 64) * NKD + u];
    for (int u = t; u < 400; u += 256) {
        int jj = u / 80, k = u - jj * 80;
        bh_s[jj][k] = (k < NKD) ? bh[k * NKD + j0 + jj] : 0.f;
    }

    int row_g = mb * 64 + w * 16 + col;
    short8v a8[5];
    #pragma unroll
    for (int ks = 0; ks < 5; ++ks) {
        const float* p = obs + (size_t)row_g * OBD + ks * 32 + q * 8;
        float4v lo = *(const float4v*)p;
        float4v hi = *(const float4v*)(p + 4);
        a8[ks] = short8v{(short)f2b(lo[0]), (short)f2b(lo[1]), (short)f2b(lo[2]), (short)f2b(lo[3]),
                         (short)f2b(hi[0]), (short)f2b(hi[1]), (short)f2b(hi[2]), (short)f2b(hi[3])};
    }
    __syncthreads();

    // Boost hyper waves over co-resident fill waves (role-diverse regime).
    __builtin_amdgcn_s_setprio(1);

    int rl = w * 16 + q * 4;                 // C rows rl..rl+3 (m89 mapping)
    for (int jj = 0; jj < 5; ++jj) {
        float sacc[4] = {0.f, 0.f, 0.f, 0.f};
        #pragma unroll
        for (int c5 = 0; c5 < 5; ++c5) {
            int k = c5 * 16 + col;           // padded key index [0,80)
            int p = sid * 400 + jj * 80 + k;
            const ushort* bp = WhTr + (size_t)p * OBD;
            float4v acc = {0.f, 0.f, 0.f, 0.f};
            #pragma unroll
            for (int ks = 0; ks < 5; ++ks) {
                short8v b8 = *(const short8v*)(bp + ks * 32 + q * 8);
                acc = __builtin_amdgcn_mfma_f32_16x16x32_bf16(a8[ks], b8, acc, 0, 0, 0);
            }
            float bias = bh_s[jj][k];
            #pragma unroll
            for (int r = 0; r < 4; ++r) {
                float kw = (k < NKD) ? kv_s[rl + r][k] : 0.f;
                sacc[r] += kw * fabsf(acc[r] + bias);
            }
        }
        #pragma unroll
        for (int r = 0; r < 4; ++r) {
            float v = sacc[r];
            v += __shfl_xor(v, 1);
            v += __shfl_xor(v, 2);
            v += __shfl_xor(v, 4);
            v += __shfl_xor(v, 8);
            if (col == 0)
                atomicAdd(&keys_acc[(size_t)(mb * 64 + rl + r) * NKD + j0 + jj], v);
        }
    }
    __builtin_amdgcn_s_setprio(0);
}

// ---------- K2 fallback (ws too small): f32 Wh loads, LDS ak, global atomics ----------
__global__ __launch_bounds__(256) void k_fuse_f32(
    const float* __restrict__ obs, const float* __restrict__ Wh,
    const float* __restrict__ bh, const float* __restrict__ kv,
    float* __restrict__ keys_acc, float* __restrict__ dense)
{
    __shared__ float kv_s[64][NKD];
    __shared__ float ak[64][NKD];
    int t = threadIdx.x;

    if (blockIdx.x >= NSPLIT_F * 64) {
        int fb = blockIdx.x - NSPLIT_F * 64;
        fill_range((float4v*)dense, (size_t)F1_N4 + (size_t)fb * 256 + t,
                   (size_t)NFILL * 256, F2_END);
        return;
    }

    int ns = blockIdx.x & 7, mb = blockIdx.x >> 3;
    int lane = t & 63, w = t >> 6;
    int q = lane >> 4, col = lane & 15;
    int cstart = ns * CPS;
    int cend = NCOL < cstart + CPS ? NCOL : cstart + CPS;

    for (int u = t; u < 64 * NKD; u += 256) {
        ((float*)kv_s)[u] = kv[(size_t)(mb * 64) * NKD + u];
        ((float*)ak)[u] = 0.f;
    }

    int row_g = mb * 64 + w * 16 + col;
    short8v a8[5];
    #pragma unroll
    for (int ks = 0; ks < 5; ++ks) {
        const float* p = obs + (size_t)row_g * OBD + ks * 32 + q * 8;
        float4v lo = *(const float4v*)p;
        float4v hi = *(const float4v*)(p + 4);
        a8[ks] = short8v{(short)f2b(lo[0]), (short)f2b(lo[1]), (short)f2b(lo[2]), (short)f2b(lo[3]),
                         (short)f2b(hi[0]), (short)f2b(hi[1]), (short)f2b(hi[2]), (short)f2b(hi[3])};
    }
    __syncthreads();

    for (int cb = cstart; cb < cend; cb += 16) {
        int c2 = cb + col;
        uint cc = (uint)(c2 < NCOL ? c2 : NCOL - 1);
        float4v acc = {0.f, 0.f, 0.f, 0.f};
        #pragma unroll
        for (int ks = 0; ks < 5; ++ks) {
            uint kbase = (uint)(ks * 32 + q * 8) * (uint)NCOL + cc;
            short8v b8;
            #pragma unroll
            for (int r = 0; r < 8; ++r)
                b8[r] = (short)f2b(Wh[kbase + (uint)r * (uint)NCOL]);
            acc = __builtin_amdgcn_mfma_f32_16x16x32_bf16(a8[ks], b8, acc, 0, 0, 0);
        }
        if (c2 < cend) {
            float bias = bh[c2];
            int k2 = c2 / NKD, j = c2 - k2 * NKD;
            #pragma unroll
            for (int r = 0; r < 4; ++r) {
                int rl = w * 16 + q * 4 + r;
                ak[rl][j] += kv_s[rl][k2] * fabsf(acc[r] + bias);
            }
        }
    }
    __syncthreads();

    for (int u = t; u < 64 * NKD; u += 256)
        atomicAdd(&keys_acc[(size_t)(mb * 64) * NKD + u], ((float*)ak)[u]);
}

// ---------- K3: [0,512) attention | [512,1024) fill chunk C ----------
__global__ __launch_bounds__(256) void k_attn(
    const float* __restrict__ aq, const float* __restrict__ states,
    const float* __restrict__ keys_acc,
    const float* __restrict__ Wq, const float* __restrict__ Wk,
    const float* __restrict__ Wv1, const float* __restrict__ bv1,
    const float* __restrict__ Wv2, const float* __restrict__ bv2,
    const float* __restrict__ Ww1, const float* __restrict__ bw1,
    const float* __restrict__ Ww2, const float* __restrict__ bw2,
    float* __restrict__ out, float* __restrict__ dense)
{
    int t = threadIdx.x;
    if (blockIdx.x >= NBATCH) {           // fill chunk C: [F2_END, DENSE_N4)
        int fb = blockIdx.x - NBATCH;
        fill_range((float4v*)dense, (size_t)F2_END + (size_t)fb * 256 + t,
                   (size_t)NF3 * 256, DENSE_N4);
        return;
    }

    int b = blockIdx.x;
    __shared__ float st_s[SDD];
    __shared__ float keys_s[NAG][NKD];
    __shared__ float q_s[32], h1_s[64], hv_s[32];
    __shared__ float kp_s[NAG][32];
    __shared__ float oh_s[NHD], hw_s[NHD];

    st_s[t] = states[(size_t)b * SDD + t];
    for (int u = t; u < NAG * NKD; u += 256) {
        int n = u / NKD, j = u - NKD * n;
        float s = keys_acc[(size_t)(b * NAG + n) * NKD + j];
        keys_s[n][j] = s > 0.f ? s : (expf(s) - 1.f);      // elu
    }
    __syncthreads();

    if (t < 32) {
        float a = 0.f;
        for (int c = 0; c < SDD; ++c) a += st_s[c] * Wq[c * 32 + t];
        q_s[t] = a;
    } else if (t < 96) {
        int z = t - 32; float a = bw1[z];
        for (int c = 0; c < SDD; ++c) a += st_s[c] * Ww1[c * 64 + z];
        h1_s[z] = fmaxf(a, 0.f);
    } else if (t < 128) {
        int z = t - 96; float a = bv1[z];
        for (int c = 0; c < SDD; ++c) a += st_s[c] * Wv1[c * 32 + z];
        hv_s[z] = fmaxf(a, 0.f);
    }
    __syncthreads();

    {   // k-proj
        int i = t >> 5, u = t & 31;
        float a = 0.f;
        for (int j = 0; j < NKD; ++j) a += keys_s[i][j] * Wk[j * 32 + u];
        kp_s[i][u] = a;
    }
    __syncthreads();

    if (t < NHD) {
        int hd = t;
        float sc[NAG], m = -1e30f;
        for (int i = 0; i < NAG; ++i) {
            float a = 0.f;
            for (int dd = 0; dd < 8; ++dd) a += q_s[hd * 8 + dd] * kp_s[i][hd * 8 + dd];
            a *= 0.35355339059327373f;
            sc[i] = a; if (a > m) m = a;
        }
        float sum = 0.f;
        for (int i = 0; i < NAG; ++i) { sc[i] = expf(sc[i] - m); sum += sc[i]; }
        float inv = 1.f / sum, oh = 0.f;
        for (int i = 0; i < NAG; ++i) {
            float at = sc[i] * inv;
            out[OUT1_OFF + (size_t)(b * NHD + hd) * NAG + i] = at;
            oh += at * aq[b * NAG + i];
        }
        oh_s[hd] = oh;
        float hw = bw2[hd];
        for (int z = 0; z < 64; ++z) hw += h1_s[z] * Ww2[z * NHD + hd];
        hw_s[hd] = hw * hw;
    }
    __syncthreads();

    if (t == 0) {
        float v = bv2[0];
        for (int z = 0; z < 32; ++z) v += hv_s[z] * Wv2[z];
        float qt = 0.f;
        for (int hd = 0; hd < NHD; ++hd) qt += oh_s[hd] * hw_s[hd];
        out[b] = qt + v;
    }
}

extern "C" void kernel_launch(void* const* d_in, const int* in_sizes, int n_in,
                              void* d_out, int out_size, void* d_ws, size_t ws_size,
                              hipStream_t stream) {
    const float* aq   = (const float*)d_in[0];
    const float* obs  = (const float*)d_in[1];
    const float* st   = (const float*)d_in[2];
    const float* Wg   = (const float*)d_in[4];
    const float* bg   = (const float*)d_in[5];
    const float* asrc = (const float*)d_in[6];
    const float* adst = (const float*)d_in[7];
    const float* Wh   = (const float*)d_in[8];
    const float* bh   = (const float*)d_in[9];
    const float* Wq_  = (const float*)d_in[10];
    const float* Wk_  = (const float*)d_in[11];
    const float* Wv1  = (const float*)d_in[12];
    const float* bv1  = (const float*)d_in[13];
    const float* Wv2  = (const float*)d_in[14];
    const float* bv2  = (const float*)d_in[15];
    const float* Ww1  = (const float*)d_in[16];
    const float* bw1  = (const float*)d_in[17];
    const float* Ww2  = (const float*)d_in[18];
    const float* bw2  = (const float*)d_in[19];
    float* out = (float*)d_out;
    float* dense = out + OUT2_OFF;

    float*  kv       = (float*)d_ws;                        // [4096][65]
    float*  keys_acc = kv + KVN;                            // [4096][65]
    ushort* WhTr     = (ushort*)((char*)d_ws + WHT_OFF);    // [5200][160] bf16
    int rpath = (ws_size >= WS_NEED) ? 1 : 0;

    // K1: gat | scattered prep | zero keys_acc | fill A
    k_pre<<<NBATCH + NPREP + NZERO + NF1, 256, 0, stream>>>(
        aq, obs, Wg, bg, asrc, adst, Wh, kv, keys_acc, WhTr, dense, rpath);

    // K2: hyper v5 (setprio-boosted) | fill B  — fused (R19 proved unfuse +35us)
    if (rpath)
        k_fuse_r<<<NHYP + NFILL, 256, 0, stream>>>(obs, WhTr, bh, kv, keys_acc, dense);
    else
        k_fuse_f32<<<NSPLIT_F * 64 + NFILL, 256, 0, stream>>>(obs, Wh, bh, kv, keys_acc, dense);

    // K3: attention | fill C
    k_attn<<<NBATCH + NF3, 256, 0, stream>>>(aq, st, keys_acc, Wq_, Wk_, Wv1, bv1,
                                             Wv2, bv2, Ww1, bw1, Ww2, bw2, out, dense);
}